// Round 7
// baseline (436.524 us; speedup 1.0000x reference)
//
#include <hip/hip_runtime.h>

#define S_  512
#define F_  64
#define H_  32
#define GQ  128   // 4*H
#define BT  8     // batch rows per block
#define NB  256   // 2048/BT -> one block per CU

#define XS  72    // x plane row stride (ushorts)
#define HS  40    // h plane row stride (ushorts)
#define GS  33    // head buffer row stride (floats)

typedef __attribute__((ext_vector_type(8))) short bf16x8;
typedef __attribute__((ext_vector_type(4))) float f32x4;

// f32 -> (bf16_hi << 16) | bf16_lo, both RNE; f ~= hi + lo with ~2^-17 rel err
__device__ __forceinline__ unsigned pack_split(float f) {
    unsigned u  = __builtin_bit_cast(unsigned, f);
    unsigned hi = (u + 0x7FFFu + ((u >> 16) & 1u)) & 0xFFFF0000u;
    float    fl = f - __builtin_bit_cast(float, hi);
    unsigned ul = __builtin_bit_cast(unsigned, fl);
    unsigned lo = (ul + 0x7FFFu + ((ul >> 16) & 1u)) >> 16;
    return hi | lo;
}

#define MFMA(A, B, C) __builtin_amdgcn_mfma_f32_16x16x32_bf16(A, B, C, 0, 0, 0)

__global__ __launch_bounds__(512, 1)
void lstm_mfma_kernel(const float* __restrict__ x,  const float* __restrict__ Wx,
                      const float* __restrict__ Wh, const float* __restrict__ bg,
                      const float* __restrict__ W1, const float* __restrict__ b1,
                      const float* __restrict__ W2, const float* __restrict__ b2,
                      const float* __restrict__ Wo, const float* __restrict__ bo,
                      float* __restrict__ out)
{
    const int tid = threadIdx.x;     // 0..511
    const int w   = tid >> 6;        // wave id
    const int L   = tid & 63;
    const int c16 = L & 15;          // col within wave's n-tile / A row
    const int kg  = L >> 4;          // k-group (8 contiguous k)
    const int bb  = blockIdx.x * BT;

    // gate-local column mapping: wave w, col c16 -> gate (c16>>2), j = 4w + (c16&3)
    const int gate = c16 >> 2;
    const int jloc = c16 & 3;
    const int jj   = (w << 2) + jloc;       // hidden unit 0..31
    const int gc   = (gate << 5) + jj;      // global gate column 0..127

    __shared__ __align__(16) unsigned short xh[4][16][XS], xl[4][16][XS];
    __shared__ __align__(16) unsigned short hh[16][HS],    hl[16][HS];
    __shared__ float Hd[3][BT][GS];         // head buffers: h, a1, a2

    // ---- B fragments (direct bf16 split) ----
    bf16x8 whh_, whl_, wx0h, wx0l, wx1h, wx1l;
#pragma unroll
    for (int i = 0; i < 8; ++i) {
        unsigned p = pack_split(Wh[(kg * 8 + i) * GQ + gc]);
        whh_[i] = (short)(unsigned short)(p >> 16);
        whl_[i] = (short)(unsigned short)(p & 0xFFFFu);
        p = pack_split(Wx[(kg * 8 + i) * GQ + gc]);
        wx0h[i] = (short)(unsigned short)(p >> 16);
        wx0l[i] = (short)(unsigned short)(p & 0xFFFFu);
        p = pack_split(Wx[(32 + kg * 8 + i) * GQ + gc]);
        wx1h[i] = (short)(unsigned short)(p >> 16);
        wx1l[i] = (short)(unsigned short)(p & 0xFFFFu);
    }
    const float bzv = bg[gc];
    const f32x4 biasC = { bzv, bzv, bzv, bzv };

    // ---- zero-init: x plane rows 8..15 (all slots); h planes fully ----
    for (int i = tid; i < 4 * 8 * (XS / 2); i += 512) {
        int slot = i / (8 * (XS / 2));
        int rem  = i - slot * 8 * (XS / 2);
        int row  = 8 + rem / (XS / 2);
        int col  = rem % (XS / 2);
        ((unsigned*)&xh[slot][row][0])[col] = 0u;
        ((unsigned*)&xl[slot][row][0])[col] = 0u;
    }
    for (int i = tid; i < 16 * (HS / 2); i += 512) {
        ((unsigned*)&hh[0][0])[i] = 0u;
        ((unsigned*)&hl[0][0])[i] = 0u;
    }

    // x staging: one float per lane; thread tid covers (row pr, col pc)
    const int pr = tid >> 6;         // batch row 0..7 (== wave id)
    const int pc = tid & 63;         // feature 0..63
    const float* xsrc = x + (size_t)(bb + pr) * S_ * F_ + pc;
#pragma unroll
    for (int tt = 0; tt < 2; ++tt) {
        unsigned p = pack_split(xsrc[(size_t)tt * F_]);
        xh[tt][pr][pc] = (unsigned short)(p >> 16);
        xl[tt][pr][pc] = (unsigned short)(p & 0xFFFFu);
    }

    float cc[4] = {0.0f, 0.0f, 0.0f, 0.0f};  // 4 cells per combine lane
    const bool istanh = (gate == 2);
    const bool isComb = (c16 < 4) && (kg < 2);   // lanes owning cells (b=kg*4+r, j=4w+c16)

    for (int t = 0; t < S_; ++t) {
        __syncthreads();   // h(t-1) and x[t] slot published

        // early-issue global load for x[t+2] (latency hidden under the step)
        float xnf = 0.0f;
        const bool doPre = (t + 2 < S_);
        if (doPre) xnf = xsrc[(size_t)(t + 2) * F_];

        // A fragments
        const int xs = t & 3;
        bf16x8 ah_h = *(const bf16x8*)&hh[c16][kg * 8];
        bf16x8 ah_l = *(const bf16x8*)&hl[c16][kg * 8];
        bf16x8 ax0h = *(const bf16x8*)&xh[xs][c16][kg * 8];
        bf16x8 ax0l = *(const bf16x8*)&xl[xs][c16][kg * 8];
        bf16x8 ax1h = *(const bf16x8*)&xh[xs][c16][32 + kg * 8];
        bf16x8 ax1l = *(const bf16x8*)&xl[xs][c16][32 + kg * 8];

        // 3 independent chains of 3 MFMAs
        f32x4 a0 = biasC;
        f32x4 a1 = { 0.0f, 0.0f, 0.0f, 0.0f };
        f32x4 a2 = { 0.0f, 0.0f, 0.0f, 0.0f };
        a0 = MFMA(ax0h, wx0h, a0);
        a1 = MFMA(ax0l, wx0h, a1);
        a2 = MFMA(ax0h, wx0l, a2);
        a0 = MFMA(ax1h, wx1h, a0);
        a1 = MFMA(ax1l, wx1h, a1);
        a2 = MFMA(ax1h, wx1l, a2);
        a0 = MFMA(ah_h, whh_, a0);
        a1 = MFMA(ah_l, whh_, a1);
        a2 = MFMA(ah_h, whl_, a2);
        f32x4 z = (a0 + a1) + a2;

        // nonlinearity (per-lane gate type, predicated)
        float gv[4];
#pragma unroll
        for (int r = 0; r < 4; ++r) {
            float zx = istanh ? 2.0f * z[r] : z[r];
            float s  = __builtin_amdgcn_rcpf(1.0f + __expf(-zx));
            gv[r] = istanh ? 2.0f * s - 1.0f : s;
        }

        // in-wave gate gather: for c16<4 (i-lane): f = +4, g = +8, o = +12
        float fS[4], gS[4], oS[4];
#pragma unroll
        for (int r = 0; r < 4; ++r) {
            float s8 = __shfl_xor(gv[r], 8);
            fS[r] = __shfl_xor(gv[r], 4);
            oS[r] = __shfl_xor(s8, 4);
            gS[r] = s8;
        }

        if (isComb) {
#pragma unroll
            for (int r = 0; r < 4; ++r) {
                float ig = gv[r] * gS[r];                 // i * g
                cc[r] = fmaf(fS[r], cc[r], ig);           // c = f*c + i*g
                float th = 2.0f * __builtin_amdgcn_rcpf(1.0f + __expf(-2.0f * cc[r])) - 1.0f;
                float hv = oS[r] * th;                    // h = o * tanh(c)
                int bq = (kg << 2) + r;                   // batch row 0..7
                unsigned p = pack_split(hv);
                hh[bq][jj] = (unsigned short)(p >> 16);
                hl[bq][jj] = (unsigned short)(p & 0xFFFFu);
                if (t == S_ - 1) Hd[0][bq][jj] = hv;
            }
        }

        // pack + publish x[t+2] (all lanes, one element each)
        if (doPre) {
            unsigned p = pack_split(xnf);
            const int s2 = (t + 2) & 3;
            xh[s2][pr][pc] = (unsigned short)(p >> 16);
            xl[s2][pr][pc] = (unsigned short)(p & 0xFFFFu);
        }
    }
    __syncthreads();

    // ---- MLP head: 32 -> 32 -> 16 -> 3, leaky_relu(0.01) ----
    if (tid < 256) {
        int rb = tid >> 5, n = tid & 31;
        float a = b1[n];
#pragma unroll
        for (int k = 0; k < 32; ++k) a = fmaf(Hd[0][rb][k], W1[k * 32 + n], a);
        a = (a > 0.0f) ? a : 0.01f * a;
        Hd[1][rb][n] = a;
    }
    __syncthreads();
    if (tid < 128) {
        int rb = tid >> 4, n = tid & 15;
        float a = b2[n];
#pragma unroll
        for (int k = 0; k < 32; ++k) a = fmaf(Hd[1][rb][k], W2[k * 16 + n], a);
        a = (a > 0.0f) ? a : 0.01f * a;
        Hd[2][rb][n] = a;
    }
    __syncthreads();
    if (tid < 24) {
        int rb = tid / 3, n = tid - rb * 3;
        float a = bo[n];
#pragma unroll
        for (int k = 0; k < 16; ++k) a = fmaf(Hd[2][rb][k], Wo[k * 3 + n], a);
        out[(size_t)(bb + rb) * 3 + n] = a;
    }
}

extern "C" void kernel_launch(void* const* d_in, const int* in_sizes, int n_in,
                              void* d_out, int out_size, void* d_ws, size_t ws_size,
                              hipStream_t stream) {
    const float* x  = (const float*)d_in[0];
    const float* Wx = (const float*)d_in[1];
    const float* Wh = (const float*)d_in[2];
    const float* bg = (const float*)d_in[3];
    const float* W1 = (const float*)d_in[4];
    const float* b1 = (const float*)d_in[5];
    const float* W2 = (const float*)d_in[6];
    const float* b2 = (const float*)d_in[7];
    const float* Wo = (const float*)d_in[8];
    const float* bo = (const float*)d_in[9];
    float* out = (float*)d_out;

    hipLaunchKernelGGL(lstm_mfma_kernel, dim3(NB), dim3(512), 0, stream,
                       x, Wx, Wh, bg, W1, b1, W2, b2, Wo, bo, out);
}

// Round 8
// 230.730 us; speedup vs baseline: 1.8919x; 1.8919x over previous
//
#include <hip/hip_runtime.h>

#define S_  512
#define F_  64
#define H_  32
#define GQ  128   // 4*H
#define BT  8     // real batch rows per block
#define NB  256   // 2048/BT -> one block per CU

#define XS  72    // x plane row stride (ushorts): b128 quad-slots uniform
#define HS  40    // h plane row stride (ushorts): b128 quad-slots uniform
#define GS  33    // head buffer row stride (floats)

typedef __attribute__((ext_vector_type(8))) short bf16x8;
typedef __attribute__((ext_vector_type(4))) float f32x4;

// f32 -> (bf16_hi << 16) | bf16_lo, both RNE; f ~= hi + lo with ~2^-17 rel err
__device__ __forceinline__ unsigned pack_split(float f) {
    unsigned u  = __builtin_bit_cast(unsigned, f);
    unsigned hi = (u + 0x7FFFu + ((u >> 16) & 1u)) & 0xFFFF0000u;
    float    fl = f - __builtin_bit_cast(float, hi);
    unsigned ul = __builtin_bit_cast(unsigned, fl);
    unsigned lo = (ul + 0x7FFFu + ((ul >> 16) & 1u)) >> 16;
    return hi | lo;
}

__device__ __forceinline__ float sigm(float z) {
    return __builtin_amdgcn_rcpf(1.0f + __expf(-z));
}
__device__ __forceinline__ float tanh_f(float z) {
    return 2.0f * __builtin_amdgcn_rcpf(1.0f + __expf(-2.0f * z)) - 1.0f;
}

#define MFMA(A, B, C) __builtin_amdgcn_mfma_f32_16x16x32_bf16(A, B, C, 0, 0, 0)

// Transposed MFMA: A = weight cols (regs), B = x/h (LDS).
// D row m = 4q+g -> (unit q, gate g); D col = batch.
// Lane (c16, kg) of wave w: D rows 4kg+r, col c16 ->
//   owns all 4 gates of cell (batch=c16, unit jj=4w+kg).
__global__ __launch_bounds__(512, 1)
void lstm_mfma_kernel(const float* __restrict__ x,  const float* __restrict__ Wx,
                      const float* __restrict__ Wh, const float* __restrict__ bg,
                      const float* __restrict__ W1, const float* __restrict__ b1,
                      const float* __restrict__ W2, const float* __restrict__ b2,
                      const float* __restrict__ Wo, const float* __restrict__ bo,
                      float* __restrict__ out)
{
    const int tid = threadIdx.x;     // 0..511
    const int w   = tid >> 6;        // wave id
    const int L   = tid & 63;
    const int c16 = L & 15;          // A row (weight-row) / B col (batch) / D col
    const int kg  = L >> 4;          // k-group AND unit-offset of D rows
    const int bb  = blockIdx.x * BT;
    const int jj  = (w << 2) + kg;   // hidden unit owned by this lane

    // A row m=c16 corresponds to original weight column:
    const int gcol = ((c16 & 3) << 5) + (w << 2) + (c16 >> 2);

    __shared__ __align__(16) unsigned short xh[4][16][XS], xl[4][16][XS];
    __shared__ __align__(16) unsigned short hh[2][16][HS], hl[2][16][HS];
    __shared__ float Hd[3][BT][GS];

    // ---- A fragments: weight columns, split hi/lo (once) ----
    bf16x8 wx0h, wx0l, wx1h, wx1l, whh_, whl_;
#pragma unroll
    for (int i = 0; i < 8; ++i) {
        unsigned p = pack_split(Wx[(kg * 8 + i) * GQ + gcol]);
        wx0h[i] = (short)(unsigned short)(p >> 16);
        wx0l[i] = (short)(unsigned short)(p & 0xFFFFu);
        p = pack_split(Wx[(32 + kg * 8 + i) * GQ + gcol]);
        wx1h[i] = (short)(unsigned short)(p >> 16);
        wx1l[i] = (short)(unsigned short)(p & 0xFFFFu);
        p = pack_split(Wh[(kg * 8 + i) * GQ + gcol]);
        whh_[i] = (short)(unsigned short)(p >> 16);
        whl_[i] = (short)(unsigned short)(p & 0xFFFFu);
    }
    // bias for D row 4kg+r = gate r of unit jj
    f32x4 biasC;
#pragma unroll
    for (int r = 0; r < 4; ++r) biasC[r] = bg[r * 32 + jj];

    // ---- zero-init: x rows 8..15 (all slots); h both parity planes ----
    for (int i = tid; i < 4 * 8 * (XS / 2); i += 512) {
        int slot = i / (8 * (XS / 2));
        int rem  = i - slot * 8 * (XS / 2);
        int row  = 8 + rem / (XS / 2);
        int col  = rem % (XS / 2);
        ((unsigned*)&xh[slot][row][0])[col] = 0u;
        ((unsigned*)&xl[slot][row][0])[col] = 0u;
    }
    for (int i = tid; i < 2 * 16 * (HS / 2); i += 512) {
        ((unsigned*)&hh[0][0][0])[i] = 0u;
        ((unsigned*)&hl[0][0][0])[i] = 0u;
    }

    // x staging: one float per lane per step
    const int pr = tid >> 6;         // batch row 0..7
    const int pc = tid & 63;         // feature
    const float* xsrc = x + (size_t)(bb + pr) * S_ * F_ + pc;
#pragma unroll
    for (int tt = 0; tt < 2; ++tt) {
        unsigned p = pack_split(xsrc[(size_t)tt * F_]);
        xh[tt][pr][pc] = (unsigned short)(p >> 16);
        xl[tt][pr][pc] = (unsigned short)(p & 0xFFFFu);
    }
    __syncthreads();

    float cc = 0.0f;

    for (int t = 0; t < S_; ++t) {
        // ---- pre-barrier: x work (slot t&3 published >=1 barrier ago) ----
        const int xs = t & 3;
        bf16x8 bx0h = *(const bf16x8*)&xh[xs][c16][kg * 8];
        bf16x8 bx0l = *(const bf16x8*)&xl[xs][c16][kg * 8];
        bf16x8 bx1h = *(const bf16x8*)&xh[xs][c16][32 + kg * 8];
        bf16x8 bx1l = *(const bf16x8*)&xl[xs][c16][32 + kg * 8];

        float xnf = 0.0f;
        const bool doPre = (t + 2 < S_);
        if (doPre) xnf = xsrc[(size_t)(t + 2) * F_];   // early HBM issue

        f32x4 a0 = biasC;
        f32x4 a1 = { 0.0f, 0.0f, 0.0f, 0.0f };
        f32x4 a2 = { 0.0f, 0.0f, 0.0f, 0.0f };
        a0 = MFMA(wx0h, bx0h, a0);    // Whi * xhi
        a1 = MFMA(wx0h, bx0l, a1);    // Whi * xlo
        a2 = MFMA(wx0l, bx0h, a2);    // Wlo * xhi
        a0 = MFMA(wx1h, bx1h, a0);
        a1 = MFMA(wx1h, bx1l, a1);
        a2 = MFMA(wx1l, bx1h, a2);

        __syncthreads();   // h(t-1) published by all waves

        // ---- post-barrier: h chain ----
        const int hp = (t & 1) ^ 1;
        bf16x8 bhh = *(const bf16x8*)&hh[hp][c16][kg * 8];
        bf16x8 bhl = *(const bf16x8*)&hl[hp][c16][kg * 8];
        a0 = MFMA(whh_, bhh, a0);
        a1 = MFMA(whh_, bhl, a1);
        a2 = MFMA(whl_, bhh, a2);
        f32x4 z = (a0 + a1) + a2;

        // gates: in-lane, static per register index
        float iv = sigm(z[0]);
        float fv = sigm(z[1]);
        float gv = tanh_f(z[2]);
        float ov = sigm(z[3]);
        cc = fmaf(fv, cc, iv * gv);
        float hv = ov * tanh_f(cc);

        const int wp = t & 1;
        unsigned p = pack_split(hv);
        hh[wp][c16][jj] = (unsigned short)(p >> 16);
        hl[wp][c16][jj] = (unsigned short)(p & 0xFFFFu);
        if (t == S_ - 1 && c16 < BT) Hd[0][c16][jj] = hv;

        // pack + publish x[t+2] (slot (t+2)&3; readers >=1 barrier away)
        if (doPre) {
            unsigned q = pack_split(xnf);
            const int s2 = (t + 2) & 3;
            xh[s2][pr][pc] = (unsigned short)(q >> 16);
            xl[s2][pr][pc] = (unsigned short)(q & 0xFFFFu);
        }
    }
    __syncthreads();

    // ---- MLP head: 32 -> 32 -> 16 -> 3, leaky_relu(0.01) ----
    if (tid < 256) {
        int rb = tid >> 5, n = tid & 31;
        float a = b1[n];
#pragma unroll
        for (int k = 0; k < 32; ++k) a = fmaf(Hd[0][rb][k], W1[k * 32 + n], a);
        a = (a > 0.0f) ? a : 0.01f * a;
        Hd[1][rb][n] = a;
    }
    __syncthreads();
    if (tid < 128) {
        int rb = tid >> 4, n = tid & 15;
        float a = b2[n];
#pragma unroll
        for (int k = 0; k < 32; ++k) a = fmaf(Hd[1][rb][k], W2[k * 16 + n], a);
        a = (a > 0.0f) ? a : 0.01f * a;
        Hd[2][rb][n] = a;
    }
    __syncthreads();
    if (tid < 24) {
        int rb = tid / 3, n = tid - rb * 3;
        float a = bo[n];
#pragma unroll
        for (int k = 0; k < 16; ++k) a = fmaf(Hd[2][rb][k], Wo[k * 3 + n], a);
        out[(size_t)(bb + rb) * 3 + n] = a;
    }
}

extern "C" void kernel_launch(void* const* d_in, const int* in_sizes, int n_in,
                              void* d_out, int out_size, void* d_ws, size_t ws_size,
                              hipStream_t stream) {
    const float* x  = (const float*)d_in[0];
    const float* Wx = (const float*)d_in[1];
    const float* Wh = (const float*)d_in[2];
    const float* bg = (const float*)d_in[3];
    const float* W1 = (const float*)d_in[4];
    const float* b1 = (const float*)d_in[5];
    const float* W2 = (const float*)d_in[6];
    const float* b2 = (const float*)d_in[7];
    const float* Wo = (const float*)d_in[8];
    const float* bo = (const float*)d_in[9];
    float* out = (float*)d_out;

    hipLaunchKernelGGL(lstm_mfma_kernel, dim3(NB), dim3(512), 0, stream,
                       x, Wx, Wh, bg, W1, b1, W2, b2, Wo, bo, out);
}